// Round 1
// baseline (537.369 us; speedup 1.0000x reference)
//
#include <hip/hip_runtime.h>

#define NNODES 50000
#define NGRAPHS 512
#define D 64
#define NCLS 10

// ---- degree ----
__global__ void k_deg(const int* __restrict__ dst, int* __restrict__ degi, int E) {
  int i = blockIdx.x * blockDim.x + threadIdx.x;
  if (i < E) atomicAdd(&degi[dst[i]], 1);
}

__global__ void k_dis(const int* __restrict__ degi, float* __restrict__ dis, int n) {
  int i = blockIdx.x * blockDim.x + threadIdx.x;
  if (i < n) dis[i] = rsqrtf((float)degi[i] + 1.0f);
}

// ---- h = (optionally gathered) x @ W ; W is 64x64 staged in LDS ----
template <bool GATHER>
__global__ void k_gemm(const float* __restrict__ x, const int* __restrict__ tokens,
                       const float* __restrict__ W, float* __restrict__ h, int n) {
  __shared__ float Ws[64][64];
  __shared__ float xs[4][64];
  int tid = threadIdx.x;
  for (int i = tid; i < 64 * 64; i += 256) Ws[i >> 6][i & 63] = W[i];
  int nl = tid >> 6, lane = tid & 63;
  int node = blockIdx.x * 4 + nl;
  if (node < n) {
    size_t row;
    if (GATHER) row = (size_t)tokens[node] * D;
    else        row = (size_t)node * D;
    xs[nl][lane] = x[row + lane];
  }
  __syncthreads();
  if (node < n) {
    float acc = 0.f;
#pragma unroll
    for (int k = 0; k < 64; ++k) acc += xs[nl][k] * Ws[k][lane];
    h[(size_t)node * D + lane] = acc;
  }
}

// ---- edge scatter: agg[dst] += h[src] * dis[src]*dis[dst], one lane per channel ----
__global__ void k_scatter(const float* __restrict__ h, const int* __restrict__ src,
                          const int* __restrict__ dst, const float* __restrict__ dis,
                          float* __restrict__ agg, int E) {
  long long tid = (long long)blockIdx.x * blockDim.x + threadIdx.x;
  int e = (int)(tid >> 6);
  int lane = (int)(tid & 63);
  if (e < E) {
    int s = src[e], d = dst[e];
    float c = dis[s] * dis[d];
    float v = h[(size_t)s * D + lane] * c;
    atomicAdd(&agg[(size_t)d * D + lane], v);
  }
}

// ---- self-loop + bias + relu (in place on agg) ----
__global__ void k_post(const float* __restrict__ h, const float* __restrict__ dis,
                       const float* __restrict__ b, float* __restrict__ agg, int n) {
  int i = blockIdx.x * blockDim.x + threadIdx.x;
  if (i < n * D) {
    int node = i >> 6, lane = i & 63;
    float dd = dis[node];
    float v = agg[i] + h[i] * dd * dd + b[lane];
    agg[i] = v > 0.f ? v : 0.f;
  }
}

// ---- pooling ----
__global__ void k_pool(const float* __restrict__ x, const int* __restrict__ batch,
                       float* __restrict__ sums, int n) {
  int i = blockIdx.x * blockDim.x + threadIdx.x;
  if (i < n * D) {
    int node = i >> 6, lane = i & 63;
    atomicAdd(&sums[(size_t)batch[node] * D + lane], x[i]);
  }
}

__global__ void k_cnt(const int* __restrict__ batch, int* __restrict__ cnt, int n) {
  int i = blockIdx.x * blockDim.x + threadIdx.x;
  if (i < n) atomicAdd(&cnt[batch[i]], 1);
}

// ---- mean + linear head ----
__global__ void k_final(const float* __restrict__ sums, const int* __restrict__ cnt,
                        const float* __restrict__ lw, const float* __restrict__ lb,
                        float* __restrict__ out) {
  int i = blockIdx.x * blockDim.x + threadIdx.x;
  if (i < NGRAPHS * NCLS) {
    int g = i / NCLS, c = i % NCLS;
    float inv = 1.0f / fmaxf((float)cnt[g], 1.0f);
    float acc = lb[c];
#pragma unroll
    for (int k = 0; k < 64; ++k) acc += sums[(size_t)g * D + k] * inv * lw[k * NCLS + c];
    out[i] = acc;
  }
}

extern "C" void kernel_launch(void* const* d_in, const int* in_sizes, int n_in,
                              void* d_out, int out_size, void* d_ws, size_t ws_size,
                              hipStream_t stream) {
  const int* tokens = (const int*)d_in[0];
  const int* edge   = (const int*)d_in[1];
  const int* batch  = (const int*)d_in[2];
  const float* emb  = (const float*)d_in[3];
  const float* W1   = (const float*)d_in[4];
  const float* b1   = (const float*)d_in[5];
  const float* W2   = (const float*)d_in[6];
  const float* b2   = (const float*)d_in[7];
  const float* lw   = (const float*)d_in[8];
  const float* lb   = (const float*)d_in[9];
  float* out = (float*)d_out;

  const int N = in_sizes[0];
  const int E = in_sizes[1] / 2;
  const int* src = edge;
  const int* dstv = edge + E;

  char* ws = (char*)d_ws;
  size_t off = 0;
  auto alloc = [&](size_t bytes) {
    void* p = ws + off;
    off += (bytes + 255) & ~(size_t)255;
    return p;
  };
  float* A    = (float*)alloc((size_t)N * D * sizeof(float));  // h buffers
  float* B    = (float*)alloc((size_t)N * D * sizeof(float));  // agg / x buffers
  float* dis  = (float*)alloc((size_t)N * sizeof(float));
  int*   degi = (int*)alloc((size_t)N * sizeof(int));
  float* sums = (float*)alloc((size_t)NGRAPHS * D * sizeof(float));
  int*   cnt  = (int*)alloc((size_t)NGRAPHS * sizeof(int));

  const int ND = N * D;
  const int edgeBlocks = (int)(((long long)E * 64 + 255) / 256);

  // degrees (shared by both layers)
  hipMemsetAsync(degi, 0, (size_t)N * sizeof(int), stream);
  k_deg<<<(E + 255) / 256, 256, 0, stream>>>(dstv, degi, E);
  k_dis<<<(N + 255) / 256, 256, 0, stream>>>(degi, dis, N);

  // layer 1: h1 = emb[tokens] @ W1 -> A
  k_gemm<true><<<(N + 3) / 4, 256, 0, stream>>>(emb, tokens, W1, A, N);
  hipMemsetAsync(B, 0, (size_t)ND * sizeof(float), stream);
  k_scatter<<<edgeBlocks, 256, 0, stream>>>(A, src, dstv, dis, B, E);
  k_post<<<(ND + 255) / 256, 256, 0, stream>>>(A, dis, b1, B, N);  // B = relu(x2)

  // layer 2: h2 = B @ W2 -> A
  k_gemm<false><<<(N + 3) / 4, 256, 0, stream>>>(B, nullptr, W2, A, N);
  hipMemsetAsync(B, 0, (size_t)ND * sizeof(float), stream);
  k_scatter<<<edgeBlocks, 256, 0, stream>>>(A, src, dstv, dis, B, E);
  k_post<<<(ND + 255) / 256, 256, 0, stream>>>(A, dis, b2, B, N);  // B = relu(x3)

  // pooling
  hipMemsetAsync(sums, 0, (size_t)NGRAPHS * D * sizeof(float), stream);
  hipMemsetAsync(cnt, 0, (size_t)NGRAPHS * sizeof(int), stream);
  k_pool<<<(ND + 255) / 256, 256, 0, stream>>>(B, batch, sums, N);
  k_cnt<<<(N + 255) / 256, 256, 0, stream>>>(batch, cnt, N);

  // head
  k_final<<<(NGRAPHS * NCLS + 255) / 256, 256, 0, stream>>>(sums, cnt, lw, lb, out);
}

// Round 2
// 380.165 us; speedup vs baseline: 1.4135x; 1.4135x over previous
//
#include <hip/hip_runtime.h>

#define NGRAPHS 512
#define D 64
#define NCLS 10
#define SCAN_T 1024

// ---- indegree histogram (int atomics, L2-resident counters) ----
__global__ void k_deg(const int* __restrict__ dst, int* __restrict__ degi, int E) {
  int i = blockIdx.x * blockDim.x + threadIdx.x;
  if (i < E) atomicAdd(&degi[dst[i]], 1);
}

// ---- single-block exclusive scan of indegree -> rowstart; also dis = rsqrt(deg+1) ----
__global__ __launch_bounds__(SCAN_T) void k_scan(const int* __restrict__ degi,
                                                 int* __restrict__ rowstart,
                                                 float* __restrict__ dis, int n) {
  __shared__ int ssum[SCAN_T];
  int t = threadIdx.x;
  int chunk = (n + SCAN_T - 1) / SCAN_T;
  int c0 = t * chunk, c1 = min(n, c0 + chunk);
  int s = 0;
  for (int i = c0; i < c1; ++i) s += degi[i];
  ssum[t] = s;
  __syncthreads();
  for (int off = 1; off < SCAN_T; off <<= 1) {
    int v = (t >= off) ? ssum[t - off] : 0;
    __syncthreads();
    ssum[t] += v;
    __syncthreads();
  }
  int base = (t > 0) ? ssum[t - 1] : 0;
  for (int i = c0; i < c1; ++i) {
    int dg = degi[i];
    rowstart[i] = base;
    base += dg;
    dis[i] = rsqrtf((float)dg + 1.0f);
  }
  if (t == SCAN_T - 1) rowstart[n] = ssum[SCAN_T - 1];
}

// ---- fill CSR: per edge store {src, coef} at rowstart[dst] + cursor ----
__global__ void k_fill(const int* __restrict__ src, const int* __restrict__ dst,
                       const float* __restrict__ dis, const int* __restrict__ rowstart,
                       int* __restrict__ cursor, int2* __restrict__ ec, int E) {
  int e = blockIdx.x * blockDim.x + threadIdx.x;
  if (e < E) {
    int s = src[e], d = dst[e];
    int pos = atomicAdd(&cursor[d], 1);
    float c = dis[s] * dis[d];
    ec[rowstart[d] + pos] = make_int2(s, __float_as_int(c));
  }
}

// ---- h = (optionally gathered) x @ W ; W staged once per block, grid-stride nodes ----
template <bool GATHER>
__global__ __launch_bounds__(256) void k_gemm(const float* __restrict__ x,
                                              const int* __restrict__ tokens,
                                              const float* __restrict__ W,
                                              float* __restrict__ h, int n) {
  __shared__ float Ws[64][64];
  __shared__ float xs[2][4][64];
  int tid = threadIdx.x;
  for (int i = tid; i < 64 * 64; i += 256) Ws[i >> 6][i & 63] = W[i];
  int nl = tid >> 6, lane = tid & 63;
  int buf = 0;
  for (int n0 = blockIdx.x * 4; n0 < n; n0 += gridDim.x * 4, buf ^= 1) {
    int node = n0 + nl;
    if (node < n) {
      size_t row = GATHER ? (size_t)tokens[node] * D : (size_t)node * D;
      xs[buf][nl][lane] = x[row + lane];
    }
    __syncthreads();
    if (node < n) {
      float acc = 0.f;
#pragma unroll
      for (int k = 0; k < 64; ++k) acc += xs[buf][nl][k] * Ws[k][lane];
      h[(size_t)node * D + lane] = acc;
    }
  }
}

// ---- gather-aggregate: one wave per node, lane = channel; fused self-loop+bias+relu ----
__global__ __launch_bounds__(256) void k_agg(const float* __restrict__ h,
                                             const int2* __restrict__ ec,
                                             const int* __restrict__ rowstart,
                                             const float* __restrict__ dis,
                                             const float* __restrict__ b,
                                             float* __restrict__ out, int n) {
  int tid = blockIdx.x * blockDim.x + threadIdx.x;
  int node = tid >> 6, lane = tid & 63;
  if (node >= n) return;
  int beg = rowstart[node], end = rowstart[node + 1];
  float acc = 0.f;
  int2 nxt;
  if (beg < end) nxt = ec[beg];
  for (int i = beg; i < end; ++i) {
    int2 cur = nxt;
    if (i + 1 < end) nxt = ec[i + 1];
    acc += h[(size_t)cur.x * D + lane] * __int_as_float(cur.y);
  }
  float dd = dis[node];
  acc += h[(size_t)node * D + lane] * dd * dd;
  acc += b[lane];
  out[(size_t)node * D + lane] = fmaxf(acc, 0.f);
}

// ---- segment bounds from sorted batch ids ----
__global__ void k_bounds(const int* __restrict__ batch, int* __restrict__ sg,
                         int* __restrict__ eg, int n) {
  int i = blockIdx.x * blockDim.x + threadIdx.x;
  if (i < n) {
    int bcur = batch[i];
    if (i == 0 || batch[i - 1] != bcur) sg[bcur] = i;
    if (i == n - 1 || batch[i + 1] != bcur) eg[bcur] = i + 1;
  }
}

// ---- mean-pool per graph: one block (4 waves) per graph ----
__global__ __launch_bounds__(256) void k_pool(const float* __restrict__ x,
                                              const int* __restrict__ sg,
                                              const int* __restrict__ eg,
                                              float* __restrict__ pooled) {
  __shared__ float red[4][64];
  int g = blockIdx.x;
  int w = threadIdx.x >> 6, lane = threadIdx.x & 63;
  int s = sg[g], e = eg[g];
  float acc = 0.f;
  for (int i = s + w; i < e; i += 4) acc += x[(size_t)i * D + lane];
  red[w][lane] = acc;
  __syncthreads();
  if (w == 0) {
    float v = red[0][lane] + red[1][lane] + red[2][lane] + red[3][lane];
    float inv = 1.0f / fmaxf((float)(e - s), 1.0f);
    pooled[(size_t)g * D + lane] = v * inv;
  }
}

// ---- linear head ----
__global__ void k_final(const float* __restrict__ pooled, const float* __restrict__ lw,
                        const float* __restrict__ lb, float* __restrict__ out) {
  int i = blockIdx.x * blockDim.x + threadIdx.x;
  if (i < NGRAPHS * NCLS) {
    int g = i / NCLS, c = i % NCLS;
    float acc = lb[c];
#pragma unroll
    for (int k = 0; k < D; ++k) acc += pooled[(size_t)g * D + k] * lw[k * NCLS + c];
    out[i] = acc;
  }
}

extern "C" void kernel_launch(void* const* d_in, const int* in_sizes, int n_in,
                              void* d_out, int out_size, void* d_ws, size_t ws_size,
                              hipStream_t stream) {
  const int* tokens = (const int*)d_in[0];
  const int* edge   = (const int*)d_in[1];
  const int* batch  = (const int*)d_in[2];
  const float* emb  = (const float*)d_in[3];
  const float* W1   = (const float*)d_in[4];
  const float* b1   = (const float*)d_in[5];
  const float* W2   = (const float*)d_in[6];
  const float* b2   = (const float*)d_in[7];
  const float* lw   = (const float*)d_in[8];
  const float* lb   = (const float*)d_in[9];
  float* out = (float*)d_out;

  const int N = in_sizes[0];
  const int E = in_sizes[1] / 2;
  const int* src  = edge;
  const int* dstv = edge + E;

  char* ws = (char*)d_ws;
  size_t off = 0;
  auto alloc = [&](size_t bytes) {
    void* p = ws + off;
    off += (bytes + 255) & ~(size_t)255;
    return p;
  };
  float* A        = (float*)alloc((size_t)N * D * sizeof(float));   // h buffer
  float* B        = (float*)alloc((size_t)N * D * sizeof(float));   // x buffer
  int2*  ec       = (int2*)alloc((size_t)E * sizeof(int2));          // CSR {src,coef}
  float* dis      = (float*)alloc((size_t)N * sizeof(float));
  int*   degi     = (int*)alloc((size_t)N * sizeof(int));
  int*   cursor   = (int*)alloc((size_t)N * sizeof(int));
  int*   rowstart = (int*)alloc(((size_t)N + 1) * sizeof(int));
  int*   sg       = (int*)alloc((size_t)NGRAPHS * sizeof(int));
  int*   eg       = (int*)alloc((size_t)NGRAPHS * sizeof(int));
  float* pooled   = (float*)alloc((size_t)NGRAPHS * D * sizeof(float));

  // zero the small int buffers (degi, cursor are adjacent; sg/eg adjacent)
  hipMemsetAsync(degi, 0, (size_t)N * sizeof(int), stream);
  hipMemsetAsync(cursor, 0, (size_t)N * sizeof(int), stream);
  hipMemsetAsync(sg, 0, (size_t)NGRAPHS * sizeof(int), stream);
  hipMemsetAsync(eg, 0, (size_t)NGRAPHS * sizeof(int), stream);

  // CSR build (shared by both layers)
  k_deg<<<(E + 255) / 256, 256, 0, stream>>>(dstv, degi, E);
  k_scan<<<1, SCAN_T, 0, stream>>>(degi, rowstart, dis, N);
  k_fill<<<(E + 255) / 256, 256, 0, stream>>>(src, dstv, dis, rowstart, cursor, ec, E);

  const int gemmGrid = 2048;

  // layer 1
  k_gemm<true><<<gemmGrid, 256, 0, stream>>>(emb, tokens, W1, A, N);
  k_agg<<<(N + 3) / 4, 256, 0, stream>>>(A, ec, rowstart, dis, b1, B, N);

  // layer 2
  k_gemm<false><<<gemmGrid, 256, 0, stream>>>(B, nullptr, W2, A, N);
  k_agg<<<(N + 3) / 4, 256, 0, stream>>>(A, ec, rowstart, dis, b2, B, N);

  // pooling + head
  k_bounds<<<(N + 255) / 256, 256, 0, stream>>>(batch, sg, eg, N);
  k_pool<<<NGRAPHS, 256, 0, stream>>>(B, sg, eg, pooled);
  k_final<<<(NGRAPHS * NCLS + 255) / 256, 256, 0, stream>>>(pooled, lw, lb, out);
}

// Round 3
// 282.861 us; speedup vs baseline: 1.8998x; 1.3440x over previous
//
#include <hip/hip_runtime.h>

#define NGRAPHS 512
#define D 64
#define NCLS 10
#define TILE 256

// ---- indegree histogram (int atomics, L2-resident counters) ----
__global__ void k_deg(const int* __restrict__ dst, int* __restrict__ degi, int E) {
  int i = blockIdx.x * blockDim.x + threadIdx.x;
  if (i < E) atomicAdd(&degi[dst[i]], 1);
}

// ---- scan phase A: per-block (256-wide tile) sum ----
__global__ __launch_bounds__(TILE) void k_part(const int* __restrict__ degi,
                                               int* __restrict__ bsum, int n) {
  __shared__ int red[TILE];
  int t = threadIdx.x;
  int i = blockIdx.x * TILE + t;
  red[t] = (i < n) ? degi[i] : 0;
  __syncthreads();
  for (int off = TILE / 2; off > 0; off >>= 1) {
    if (t < off) red[t] += red[t + off];
    __syncthreads();
  }
  if (t == 0) bsum[blockIdx.x] = red[0];
}

// ---- scan phase B: exclusive scan of block sums (single small block) ----
__global__ __launch_bounds__(TILE) void k_scanb(const int* __restrict__ bsum,
                                                int* __restrict__ boff, int nb) {
  __shared__ int s[TILE];
  int t = threadIdx.x;
  s[t] = (t < nb) ? bsum[t] : 0;
  __syncthreads();
  for (int off = 1; off < TILE; off <<= 1) {
    int v = (t >= off) ? s[t - off] : 0;
    __syncthreads();
    s[t] += v;
    __syncthreads();
  }
  if (t < nb) boff[t] = (t > 0) ? s[t - 1] : 0;
}

// ---- scan phase C: in-block exclusive scan + offset -> rowstart; dis = rsqrt(deg+1) ----
__global__ __launch_bounds__(TILE) void k_emit(const int* __restrict__ degi,
                                               const int* __restrict__ boff,
                                               int* __restrict__ rowstart,
                                               float* __restrict__ dis, int n) {
  __shared__ int s[TILE];
  int t = threadIdx.x;
  int i = blockIdx.x * TILE + t;
  int v = (i < n) ? degi[i] : 0;
  s[t] = v;
  __syncthreads();
  for (int off = 1; off < TILE; off <<= 1) {
    int u = (t >= off) ? s[t - off] : 0;
    __syncthreads();
    s[t] += u;
    __syncthreads();
  }
  if (i < n) {
    int incl = s[t] + boff[blockIdx.x];
    rowstart[i] = incl - v;            // exclusive
    dis[i] = rsqrtf((float)v + 1.0f);
    if (i == n - 1) rowstart[n] = incl;
  }
}

// ---- fill CSR: per edge store {src, coef} at rowstart[dst] + cursor ----
__global__ void k_fill(const int* __restrict__ src, const int* __restrict__ dst,
                       const float* __restrict__ dis, const int* __restrict__ rowstart,
                       int* __restrict__ cursor, int2* __restrict__ ec, int E) {
  int e = blockIdx.x * blockDim.x + threadIdx.x;
  if (e < E) {
    int s = src[e], d = dst[e];
    int pos = atomicAdd(&cursor[d], 1);
    float c = dis[s] * dis[d];
    ec[rowstart[d] + pos] = make_int2(s, __float_as_int(c));
  }
}

// ---- h = (optionally gathered) x @ W ; W staged once per block, grid-stride nodes ----
template <bool GATHER>
__global__ __launch_bounds__(256) void k_gemm(const float* __restrict__ x,
                                              const int* __restrict__ tokens,
                                              const float* __restrict__ W,
                                              float* __restrict__ h, int n) {
  __shared__ float Ws[64][64];
  __shared__ float xs[2][4][64];
  int tid = threadIdx.x;
  for (int i = tid; i < 64 * 64; i += 256) Ws[i >> 6][i & 63] = W[i];
  int nl = tid >> 6, lane = tid & 63;
  int buf = 0;
  for (int n0 = blockIdx.x * 4; n0 < n; n0 += gridDim.x * 4, buf ^= 1) {
    int node = n0 + nl;
    if (node < n) {
      size_t row = GATHER ? (size_t)tokens[node] * D : (size_t)node * D;
      xs[buf][nl][lane] = x[row + lane];
    }
    __syncthreads();
    if (node < n) {
      float acc = 0.f;
#pragma unroll
      for (int k = 0; k < 64; ++k) acc += xs[buf][nl][k] * Ws[k][lane];
      h[(size_t)node * D + lane] = acc;
    }
  }
}

// ---- gather-aggregate: one wave per node, lane = channel; fused self-loop+bias+relu ----
__global__ __launch_bounds__(256) void k_agg(const float* __restrict__ h,
                                             const int2* __restrict__ ec,
                                             const int* __restrict__ rowstart,
                                             const float* __restrict__ dis,
                                             const float* __restrict__ b,
                                             float* __restrict__ out, int n) {
  int tid = blockIdx.x * blockDim.x + threadIdx.x;
  int node = tid >> 6, lane = tid & 63;
  if (node >= n) return;
  int beg = rowstart[node], end = rowstart[node + 1];
  float acc = 0.f;
  int2 nxt;
  if (beg < end) nxt = ec[beg];
  for (int i = beg; i < end; ++i) {
    int2 cur = nxt;
    if (i + 1 < end) nxt = ec[i + 1];
    acc += h[(size_t)cur.x * D + lane] * __int_as_float(cur.y);
  }
  float dd = dis[node];
  acc += h[(size_t)node * D + lane] * dd * dd;
  acc += b[lane];
  out[(size_t)node * D + lane] = fmaxf(acc, 0.f);
}

// ---- segment bounds from sorted batch ids ----
__global__ void k_bounds(const int* __restrict__ batch, int* __restrict__ sg,
                         int* __restrict__ eg, int n) {
  int i = blockIdx.x * blockDim.x + threadIdx.x;
  if (i < n) {
    int bcur = batch[i];
    if (i == 0 || batch[i - 1] != bcur) sg[bcur] = i;
    if (i == n - 1 || batch[i + 1] != bcur) eg[bcur] = i + 1;
  }
}

// ---- mean-pool per graph: one block (4 waves) per graph ----
__global__ __launch_bounds__(256) void k_pool(const float* __restrict__ x,
                                              const int* __restrict__ sg,
                                              const int* __restrict__ eg,
                                              float* __restrict__ pooled) {
  __shared__ float red[4][64];
  int g = blockIdx.x;
  int w = threadIdx.x >> 6, lane = threadIdx.x & 63;
  int s = sg[g], e = eg[g];
  float acc = 0.f;
  for (int i = s + w; i < e; i += 4) acc += x[(size_t)i * D + lane];
  red[w][lane] = acc;
  __syncthreads();
  if (w == 0) {
    float v = red[0][lane] + red[1][lane] + red[2][lane] + red[3][lane];
    float inv = 1.0f / fmaxf((float)(e - s), 1.0f);
    pooled[(size_t)g * D + lane] = v * inv;
  }
}

// ---- linear head ----
__global__ void k_final(const float* __restrict__ pooled, const float* __restrict__ lw,
                        const float* __restrict__ lb, float* __restrict__ out) {
  int i = blockIdx.x * blockDim.x + threadIdx.x;
  if (i < NGRAPHS * NCLS) {
    int g = i / NCLS, c = i % NCLS;
    float acc = lb[c];
#pragma unroll
    for (int k = 0; k < D; ++k) acc += pooled[(size_t)g * D + k] * lw[k * NCLS + c];
    out[i] = acc;
  }
}

extern "C" void kernel_launch(void* const* d_in, const int* in_sizes, int n_in,
                              void* d_out, int out_size, void* d_ws, size_t ws_size,
                              hipStream_t stream) {
  const int* tokens = (const int*)d_in[0];
  const int* edge   = (const int*)d_in[1];
  const int* batch  = (const int*)d_in[2];
  const float* emb  = (const float*)d_in[3];
  const float* W1   = (const float*)d_in[4];
  const float* b1   = (const float*)d_in[5];
  const float* W2   = (const float*)d_in[6];
  const float* b2   = (const float*)d_in[7];
  const float* lw   = (const float*)d_in[8];
  const float* lb   = (const float*)d_in[9];
  float* out = (float*)d_out;

  const int N = in_sizes[0];
  const int E = in_sizes[1] / 2;
  const int* src  = edge;
  const int* dstv = edge + E;

  const int nb = (N + TILE - 1) / TILE;   // scan blocks (196 for N=50000)

  char* ws = (char*)d_ws;
  size_t off = 0;
  auto alloc = [&](size_t bytes) {
    void* p = ws + off;
    off += (bytes + 255) & ~(size_t)255;
    return p;
  };
  float* A        = (float*)alloc((size_t)N * D * sizeof(float));   // h buffer
  float* B        = (float*)alloc((size_t)N * D * sizeof(float));   // x buffer
  int2*  ec       = (int2*)alloc((size_t)E * sizeof(int2));          // CSR {src,coef}
  float* dis      = (float*)alloc((size_t)N * sizeof(float));
  int*   degi     = (int*)alloc((size_t)N * sizeof(int));
  int*   cursor   = (int*)alloc((size_t)N * sizeof(int));
  int*   rowstart = (int*)alloc(((size_t)N + 1) * sizeof(int));
  int*   bsum     = (int*)alloc((size_t)nb * sizeof(int));
  int*   boff     = (int*)alloc((size_t)nb * sizeof(int));
  int*   sg       = (int*)alloc((size_t)NGRAPHS * sizeof(int));
  int*   eg       = (int*)alloc((size_t)NGRAPHS * sizeof(int));
  float* pooled   = (float*)alloc((size_t)NGRAPHS * D * sizeof(float));

  hipMemsetAsync(degi, 0, (size_t)N * sizeof(int), stream);
  hipMemsetAsync(cursor, 0, (size_t)N * sizeof(int), stream);
  hipMemsetAsync(sg, 0, (size_t)NGRAPHS * sizeof(int), stream);
  hipMemsetAsync(eg, 0, (size_t)NGRAPHS * sizeof(int), stream);

  // CSR build (shared by both layers)
  k_deg<<<(E + 255) / 256, 256, 0, stream>>>(dstv, degi, E);
  k_part<<<nb, TILE, 0, stream>>>(degi, bsum, N);
  k_scanb<<<1, TILE, 0, stream>>>(bsum, boff, nb);
  k_emit<<<nb, TILE, 0, stream>>>(degi, boff, rowstart, dis, N);
  k_fill<<<(E + 255) / 256, 256, 0, stream>>>(src, dstv, dis, rowstart, cursor, ec, E);

  const int gemmGrid = 2048;

  // layer 1
  k_gemm<true><<<gemmGrid, 256, 0, stream>>>(emb, tokens, W1, A, N);
  k_agg<<<(N + 3) / 4, 256, 0, stream>>>(A, ec, rowstart, dis, b1, B, N);

  // layer 2
  k_gemm<false><<<gemmGrid, 256, 0, stream>>>(B, nullptr, W2, A, N);
  k_agg<<<(N + 3) / 4, 256, 0, stream>>>(A, ec, rowstart, dis, b2, B, N);

  // pooling + head
  k_bounds<<<(N + 255) / 256, 256, 0, stream>>>(batch, sg, eg, N);
  k_pool<<<NGRAPHS, 256, 0, stream>>>(B, sg, eg, pooled);
  k_final<<<(NGRAPHS * NCLS + 255) / 256, 256, 0, stream>>>(pooled, lw, lb, out);
}

// Round 4
// 228.615 us; speedup vs baseline: 2.3505x; 1.2373x over previous
//
#include <hip/hip_runtime.h>

#define NGRAPHS 512
#define D 64
#define NCLS 10
#define TILE 256

// ---- indegree histogram (int atomics, L2-resident counters) ----
__global__ void k_deg(const int* __restrict__ dst, int* __restrict__ degi, int E) {
  int i = blockIdx.x * blockDim.x + threadIdx.x;
  if (i < E) atomicAdd(&degi[dst[i]], 1);
}

// ---- scan phase A: per-block (256-wide tile) sum ----
__global__ __launch_bounds__(TILE) void k_part(const int* __restrict__ degi,
                                               int* __restrict__ bsum, int n) {
  __shared__ int red[TILE];
  int t = threadIdx.x;
  int i = blockIdx.x * TILE + t;
  red[t] = (i < n) ? degi[i] : 0;
  __syncthreads();
  for (int off = TILE / 2; off > 0; off >>= 1) {
    if (t < off) red[t] += red[t + off];
    __syncthreads();
  }
  if (t == 0) bsum[blockIdx.x] = red[0];
}

// ---- scan phase B: exclusive scan of block sums (single small block) ----
__global__ __launch_bounds__(TILE) void k_scanb(const int* __restrict__ bsum,
                                                int* __restrict__ boff, int nb) {
  __shared__ int s[TILE];
  int t = threadIdx.x;
  s[t] = (t < nb) ? bsum[t] : 0;
  __syncthreads();
  for (int off = 1; off < TILE; off <<= 1) {
    int v = (t >= off) ? s[t - off] : 0;
    __syncthreads();
    s[t] += v;
    __syncthreads();
  }
  if (t < nb) boff[t] = (t > 0) ? s[t - 1] : 0;
}

// ---- scan phase C: in-block exclusive scan + offset -> rowstart; dis = rsqrt(deg+1) ----
__global__ __launch_bounds__(TILE) void k_emit(const int* __restrict__ degi,
                                               const int* __restrict__ boff,
                                               int* __restrict__ rowstart,
                                               float* __restrict__ dis, int n) {
  __shared__ int s[TILE];
  int t = threadIdx.x;
  int i = blockIdx.x * TILE + t;
  int v = (i < n) ? degi[i] : 0;
  s[t] = v;
  __syncthreads();
  for (int off = 1; off < TILE; off <<= 1) {
    int u = (t >= off) ? s[t - off] : 0;
    __syncthreads();
    s[t] += u;
    __syncthreads();
  }
  if (i < n) {
    int incl = s[t] + boff[blockIdx.x];
    rowstart[i] = incl - v;            // exclusive
    dis[i] = rsqrtf((float)v + 1.0f);
    if (i == n - 1) rowstart[n] = incl;
  }
}

// ---- fill CSR: per edge store {src, coef} at rowstart[dst] + cursor ----
__global__ void k_fill(const int* __restrict__ src, const int* __restrict__ dst,
                       const float* __restrict__ dis, const int* __restrict__ rowstart,
                       int* __restrict__ cursor, int2* __restrict__ ec, int E) {
  int e = blockIdx.x * blockDim.x + threadIdx.x;
  if (e < E) {
    int s = src[e], d = dst[e];
    int pos = atomicAdd(&cursor[d], 1);
    float c = dis[s] * dis[d];
    ec[rowstart[d] + pos] = make_int2(s, __float_as_int(c));
  }
}

// ---- h = (optionally gathered) x @ W ; W staged once per block, grid-stride nodes ----
template <bool GATHER>
__global__ __launch_bounds__(256) void k_gemm(const float* __restrict__ x,
                                              const int* __restrict__ tokens,
                                              const float* __restrict__ W,
                                              float* __restrict__ h, int n) {
  __shared__ float Ws[64][64];
  __shared__ float xs[2][4][64];
  int tid = threadIdx.x;
  for (int i = tid; i < 64 * 64; i += 256) Ws[i >> 6][i & 63] = W[i];
  int nl = tid >> 6, lane = tid & 63;
  int buf = 0;
  for (int n0 = blockIdx.x * 4; n0 < n; n0 += gridDim.x * 4, buf ^= 1) {
    int node = n0 + nl;
    if (node < n) {
      size_t row = GATHER ? (size_t)tokens[node] * D : (size_t)node * D;
      xs[buf][nl][lane] = x[row + lane];
    }
    __syncthreads();
    if (node < n) {
      float acc = 0.f;
#pragma unroll
      for (int k = 0; k < 64; ++k) acc += xs[buf][nl][k] * Ws[k][lane];
      h[(size_t)node * D + lane] = acc;
    }
  }
}

// ---- gather-aggregate, MLP version: wave = node; lane = (edge-slot[2b] , chan-group[4b])
//      each lane holds float4 of 4 channels; 4 edges in flight, x2 unroll = 8 gathers ----
__global__ __launch_bounds__(256) void k_agg(const float4* __restrict__ h4,
                                             const int2* __restrict__ ec,
                                             const int* __restrict__ rowstart,
                                             const float* __restrict__ dis,
                                             const float4* __restrict__ b4,
                                             float4* __restrict__ out, int n) {
  int tid = blockIdx.x * blockDim.x + threadIdx.x;
  int node = tid >> 6;
  int lane = tid & 63;
  int slot = lane >> 4;    // 0..3: which edge of a 4-edge group
  int cg   = lane & 15;    // channel group: channels 4*cg .. 4*cg+3
  if (node >= n) return;
  int beg = rowstart[node], end = rowstart[node + 1];
  float4 acc = make_float4(0.f, 0.f, 0.f, 0.f);
  int i = beg + slot;
  for (; i + 4 < end; i += 8) {           // 2 edges per slot per trip
    int2 e0 = ec[i];
    int2 e1 = ec[i + 4];
    float c0 = __int_as_float(e0.y);
    float c1 = __int_as_float(e1.y);
    float4 v0 = h4[(size_t)e0.x * 16 + cg];
    float4 v1 = h4[(size_t)e1.x * 16 + cg];
    acc.x += v0.x * c0; acc.y += v0.y * c0; acc.z += v0.z * c0; acc.w += v0.w * c0;
    acc.x += v1.x * c1; acc.y += v1.y * c1; acc.z += v1.z * c1; acc.w += v1.w * c1;
  }
  if (i < end) {
    int2 e = ec[i];
    float c = __int_as_float(e.y);
    float4 v = h4[(size_t)e.x * 16 + cg];
    acc.x += v.x * c; acc.y += v.y * c; acc.z += v.z * c; acc.w += v.w * c;
  }
  // reduce the 4 edge slots (lane bits 4 and 5)
  acc.x += __shfl_xor(acc.x, 16, 64);
  acc.y += __shfl_xor(acc.y, 16, 64);
  acc.z += __shfl_xor(acc.z, 16, 64);
  acc.w += __shfl_xor(acc.w, 16, 64);
  acc.x += __shfl_xor(acc.x, 32, 64);
  acc.y += __shfl_xor(acc.y, 32, 64);
  acc.z += __shfl_xor(acc.z, 32, 64);
  acc.w += __shfl_xor(acc.w, 32, 64);
  if (slot == 0) {
    float dd = dis[node];
    float s = dd * dd;
    float4 hv = h4[(size_t)node * 16 + cg];
    float4 bv = b4[cg];
    acc.x = fmaxf(acc.x + hv.x * s + bv.x, 0.f);
    acc.y = fmaxf(acc.y + hv.y * s + bv.y, 0.f);
    acc.z = fmaxf(acc.z + hv.z * s + bv.z, 0.f);
    acc.w = fmaxf(acc.w + hv.w * s + bv.w, 0.f);
    out[(size_t)node * 16 + cg] = acc;
  }
}

// ---- segment bounds from sorted batch ids ----
__global__ void k_bounds(const int* __restrict__ batch, int* __restrict__ sg,
                         int* __restrict__ eg, int n) {
  int i = blockIdx.x * blockDim.x + threadIdx.x;
  if (i < n) {
    int bcur = batch[i];
    if (i == 0 || batch[i - 1] != bcur) sg[bcur] = i;
    if (i == n - 1 || batch[i + 1] != bcur) eg[bcur] = i + 1;
  }
}

// ---- mean-pool per graph: one block (4 waves) per graph ----
__global__ __launch_bounds__(256) void k_pool(const float* __restrict__ x,
                                              const int* __restrict__ sg,
                                              const int* __restrict__ eg,
                                              float* __restrict__ pooled) {
  __shared__ float red[4][64];
  int g = blockIdx.x;
  int w = threadIdx.x >> 6, lane = threadIdx.x & 63;
  int s = sg[g], e = eg[g];
  float acc = 0.f;
  for (int i = s + w; i < e; i += 4) acc += x[(size_t)i * D + lane];
  red[w][lane] = acc;
  __syncthreads();
  if (w == 0) {
    float v = red[0][lane] + red[1][lane] + red[2][lane] + red[3][lane];
    float inv = 1.0f / fmaxf((float)(e - s), 1.0f);
    pooled[(size_t)g * D + lane] = v * inv;
  }
}

// ---- linear head ----
__global__ void k_final(const float* __restrict__ pooled, const float* __restrict__ lw,
                        const float* __restrict__ lb, float* __restrict__ out) {
  int i = blockIdx.x * blockDim.x + threadIdx.x;
  if (i < NGRAPHS * NCLS) {
    int g = i / NCLS, c = i % NCLS;
    float acc = lb[c];
#pragma unroll
    for (int k = 0; k < D; ++k) acc += pooled[(size_t)g * D + k] * lw[k * NCLS + c];
    out[i] = acc;
  }
}

extern "C" void kernel_launch(void* const* d_in, const int* in_sizes, int n_in,
                              void* d_out, int out_size, void* d_ws, size_t ws_size,
                              hipStream_t stream) {
  const int* tokens = (const int*)d_in[0];
  const int* edge   = (const int*)d_in[1];
  const int* batch  = (const int*)d_in[2];
  const float* emb  = (const float*)d_in[3];
  const float* W1   = (const float*)d_in[4];
  const float* b1   = (const float*)d_in[5];
  const float* W2   = (const float*)d_in[6];
  const float* b2   = (const float*)d_in[7];
  const float* lw   = (const float*)d_in[8];
  const float* lb   = (const float*)d_in[9];
  float* out = (float*)d_out;

  const int N = in_sizes[0];
  const int E = in_sizes[1] / 2;
  const int* src  = edge;
  const int* dstv = edge + E;

  const int nb = (N + TILE - 1) / TILE;   // scan blocks (196 for N=50000)

  char* ws = (char*)d_ws;
  size_t off = 0;
  auto alloc = [&](size_t bytes) {
    void* p = ws + off;
    off += (bytes + 255) & ~(size_t)255;
    return p;
  };
  float* A        = (float*)alloc((size_t)N * D * sizeof(float));   // h buffer
  float* B        = (float*)alloc((size_t)N * D * sizeof(float));   // x buffer
  int2*  ec       = (int2*)alloc((size_t)E * sizeof(int2));          // CSR {src,coef}
  float* dis      = (float*)alloc((size_t)N * sizeof(float));
  int*   degi     = (int*)alloc((size_t)N * sizeof(int));
  int*   cursor   = (int*)alloc((size_t)N * sizeof(int));
  int*   rowstart = (int*)alloc(((size_t)N + 1) * sizeof(int));
  int*   bsum     = (int*)alloc((size_t)nb * sizeof(int));
  int*   boff     = (int*)alloc((size_t)nb * sizeof(int));
  int*   sg       = (int*)alloc((size_t)NGRAPHS * sizeof(int));
  int*   eg       = (int*)alloc((size_t)NGRAPHS * sizeof(int));
  float* pooled   = (float*)alloc((size_t)NGRAPHS * D * sizeof(float));

  hipMemsetAsync(degi, 0, (size_t)N * sizeof(int), stream);
  hipMemsetAsync(cursor, 0, (size_t)N * sizeof(int), stream);
  hipMemsetAsync(sg, 0, (size_t)NGRAPHS * sizeof(int), stream);
  hipMemsetAsync(eg, 0, (size_t)NGRAPHS * sizeof(int), stream);

  // CSR build (shared by both layers)
  k_deg<<<(E + 255) / 256, 256, 0, stream>>>(dstv, degi, E);
  k_part<<<nb, TILE, 0, stream>>>(degi, bsum, N);
  k_scanb<<<1, TILE, 0, stream>>>(bsum, boff, nb);
  k_emit<<<nb, TILE, 0, stream>>>(degi, boff, rowstart, dis, N);
  k_fill<<<(E + 255) / 256, 256, 0, stream>>>(src, dstv, dis, rowstart, cursor, ec, E);

  const int gemmGrid = 2048;

  // layer 1
  k_gemm<true><<<gemmGrid, 256, 0, stream>>>(emb, tokens, W1, A, N);
  k_agg<<<(N + 3) / 4, 256, 0, stream>>>((const float4*)A, ec, rowstart, dis,
                                         (const float4*)b1, (float4*)B, N);

  // layer 2
  k_gemm<false><<<gemmGrid, 256, 0, stream>>>(B, nullptr, W2, A, N);
  k_agg<<<(N + 3) / 4, 256, 0, stream>>>((const float4*)A, ec, rowstart, dis,
                                         (const float4*)b2, (float4*)B, N);

  // pooling + head
  k_bounds<<<(N + 255) / 256, 256, 0, stream>>>(batch, sg, eg, N);
  k_pool<<<NGRAPHS, 256, 0, stream>>>(B, sg, eg, pooled);
  k_final<<<(NGRAPHS * NCLS + 255) / 256, 256, 0, stream>>>(pooled, lw, lb, out);
}